// Round 16
// baseline (312.050 us; speedup 1.0000x reference)
//
#include <hip/hip_runtime.h>
#include <math.h>

// Problem constants
#define HI 1024
#define WI 1024
#define HO 512
#define WO 512
#define CIN 64
#define COUT 128
#define NW (9*CIN*COUT)   // 73728 fused 3x3 weights

typedef __attribute__((ext_vector_type(8))) short bf16x8;
typedef __attribute__((ext_vector_type(4))) float f32x4;

// Buffer plan:
//   d_out[0 .. 33.5MB) : xd, TRANSPOSED layout: px(gr,gc) at ((gc*512+gr)*64+c)
//                        -- dead before k_gelu overwrites d_out
//   ws layout (bytes):
//     yb     : 0         .. 67108864   (512*512*128 bf16 conv output)
//     Bpk    : 67108864  .. 67256320   (9*2*8*64*8 bf16, MFMA-fragment order)
//     bf     : 67256320  .. 67256832   (128 f32 fused bias)
//     part   : 67256832  .. 67322368   (256 blocks * 64 f32 partials)
//     params : 67322368  .. 67322624   (mu[32], inv_std[32])
//     zeroz  : 67519232  .. 67519360   (128B zeros for OOB halo DMA source)

#define GLDS(g, l) __builtin_amdgcn_global_load_lds( \
    (const __attribute__((address_space(1))) void*)(g), \
    (__attribute__((address_space(3))) void*)(l), 16, 0, 0)

__device__ __forceinline__ unsigned short f2bf(float f) {   // round-to-nearest-even
    unsigned u = __float_as_uint(f);
    u += 0x7fffu + ((u >> 16) & 1u);
    return (unsigned short)(u >> 16);
}

// K1: merged prep kernel (unchanged). Blocks [0,8192): bilinear downsample
// (reference's transposed sampling: out px (i,j) samples x(row=j*step, col=i*step),
// OOB zero-fill); i fast -> streaming reads; transposed xd -> contiguous writes.
// Blocks [8192,8481): weight fold+pack, bias fold, zero scratch.
__global__ void k_prep(const float* __restrict__ x,
                       const float* __restrict__ W1, const float* __restrict__ b1,
                       const float* __restrict__ W2, const float* __restrict__ b2,
                       unsigned short* __restrict__ xd,
                       unsigned short* __restrict__ Bpk, float* __restrict__ bf,
                       unsigned short* __restrict__ zeroz) {
    int bid = blockIdx.x;
    if (bid < 8192) {
        int t = bid * 256 + threadIdx.x;   // 2,097,152 threads, 8 channels each
        int c8 = t & 7;
        int i  = (t >> 3) & (WO - 1);      // FAST: x column coordinate source
        int j  = t >> 12;                  // slow: x row coordinate source
        const float step = 1024.0f / 511.0f;
        float tr = (float)j * step;        // x row coordinate (transposed sampling!)
        float tc = (float)i * step;        // x col coordinate
        int r0 = (int)tr; float fr = tr - (float)r0;
        int c0 = (int)tc; float fc = tc - (float)c0;
        float w00 = (1.f - fr) * (1.f - fc);
        float w01 = (1.f - fr) * fc;
        float w10 = fr * (1.f - fc);
        float w11 = fr * fc;
        float a0 = 0.f, a1 = 0.f, a2 = 0.f, a3 = 0.f;
        float a4 = 0.f, a5 = 0.f, a6 = 0.f, a7 = 0.f;
        const float* xb = x + (c8 << 3);
        #define TAP(R, C, W) \
            if ((R) < HI && (C) < WI) { \
                const float* p = xb + ((((R) << 10) + (C)) << 6); \
                float4 v0 = *(const float4*)p; \
                float4 v1 = *(const float4*)(p + 4); \
                a0 += (W) * v0.x; a1 += (W) * v0.y; a2 += (W) * v0.z; a3 += (W) * v0.w; \
                a4 += (W) * v1.x; a5 += (W) * v1.y; a6 += (W) * v1.z; a7 += (W) * v1.w; \
            }
        TAP(r0,     c0,     w00)
        TAP(r0,     c0 + 1, w01)
        TAP(r0 + 1, c0,     w10)
        TAP(r0 + 1, c0 + 1, w11)
        #undef TAP
        uint4 pk;
        pk.x = (unsigned)f2bf(a0) | ((unsigned)f2bf(a1) << 16);
        pk.y = (unsigned)f2bf(a2) | ((unsigned)f2bf(a3) << 16);
        pk.z = (unsigned)f2bf(a4) | ((unsigned)f2bf(a5) << 16);
        pk.w = (unsigned)f2bf(a6) | ((unsigned)f2bf(a7) << 16);
        // TRANSPOSED store: px (i,j) -> ((j*512 + i)*64 + c8*8); contiguous in i
        *(uint4*)&xd[(((j << 9) + i) << 6) + (c8 << 3)] = pk;
    } else {
        int idx = (bid - 8192) * 256 + threadIdx.x;
        if (idx < NW) {
            int j  = idx & 7;
            int l  = (idx >> 3) & 63;
            int nf = (idx >> 9) & 7;
            int h  = (idx >> 12) & 1;
            int t  = idx >> 13;
            int cin  = (h << 5) + ((l >> 4) << 3) + j;
            int cout = (nf << 4) + (l & 15);
            float v = W1[(t * 64 + cin) * 128 + cout];
            if (t == 4) v += W2[cin * 128 + cout];   // center tap gets the 1x1 conv
            Bpk[idx] = f2bf(v);
        } else if (idx < NW + COUT) {
            int c = idx - NW;
            bf[c] = b1[c] + b2[c];
        } else if (idx < NW + COUT + 64) {
            zeroz[idx - NW - COUT] = 0;
        }
    }
}

// K2: persistent double-buffered MFMA conv with FULLY REGISTER-RESIDENT B:
// each wave loads its cout-half's entire weight set (72 bf16x8 = 144 VGPR) once,
// so the K-loop is pure {4 ds_read -> 16 MFMA} (no global loads). Tap loop fully
// unrolled (breg indices must be compile-time constants). 256 blocks (1/CU) x
// 512 threads (8 waves); transposed xd, col-major halo staging via DMA.
__global__ __launch_bounds__(512, 2) void k_conv(
        const unsigned short* __restrict__ xd,
        const unsigned short* __restrict__ Bpk,
        const float* __restrict__ bf,
        const unsigned short* __restrict__ zeroz,
        unsigned short* __restrict__ yb, float* __restrict__ part) {
    __shared__ short lxs[2][324 * 64];     // 2 x (18 cols x 18 rows) x 64cin bf16 (82944 B)
    __shared__ float sred[8][32];

    const int tid = threadIdx.x;
    const int l   = tid & 63;
    const int w   = tid >> 6;
    const int trow = blockIdx.x >> 3;      // 32 tile-rows
    const int tcq  = blockIdx.x & 7;       // 8 column-quads
    const int gr0  = trow << 4;
    const int gc0b = (tcq << 2) << 4;      // first tile's gc0

    const int wq  = w & 3;                 // px quadrant
    const int wh  = w >> 2;                // cout half
    const int qg  = l >> 4;
    const int p15 = l & 15;
    const int wr0 = (wq >> 1) << 3;
    const int wc0 = (wq & 1) << 3;
    const int colbase = wc0 + (l & 7);
    // A-read base per mf in the [col][row] tile: (colbase*18 + row)*128
    int abase[4];
    #pragma unroll
    for (int mf = 0; mf < 4; ++mf)
        abase[mf] = (colbase * 18 + wr0 + 2 * mf + (p15 >> 3)) * 128;

    const bf16x8* Bbase = (const bf16x8*)Bpk;
    // ALL B fragments for this wave's cout-half: 18 K-steps x 4 nf = 72 frags (144 VGPR),
    // loaded once, resident for the whole kernel. Issued before staging -> overlaps DMA.
    bf16x8 breg[72];
    #pragma unroll
    for (int th = 0; th < 18; ++th)
        #pragma unroll
        for (int nf = 0; nf < 4; ++nf)
            breg[th * 4 + nf] = Bbase[(th << 9) + (((wh << 2) + nf) << 6) + l];
    f32x4 bias4 = *(const f32x4*)&bf[(wh << 6) + (qg << 2)];

    auto STAGE = [&](int bufi, int gc0t) {
        #pragma unroll
        for (int k = 0; k < 6; ++k) {
            int idx = tid + (k << 9);
            if (idx < 324 * 8) {
                int pos = idx >> 3, c = idx & 7;
                int col = (pos * 57) >> 10;            // pos/18: halo COLUMN
                int row = pos - col * 18;              // halo row
                int gr = gr0 + row - 1, gc = gc0t + col - 1;
                bool inpx = (gr >= 0) && (gr < HO) && (gc >= 0) && (gc < WO);
                // transposed xd: px(gr,gc) at ((gc*512+gr)*64); consecutive row -> +128B
                const unsigned short* src = inpx
                    ? xd + (((gc << 9) + gr) << 6) + ((c ^ (col & 7)) << 3)
                    : zeroz;
                GLDS(src, (char*)lxs[bufi] + (((w << 6) + (k << 9)) << 4));
            }
        }
    };

    float s[4], s2[4];
    #pragma unroll
    for (int nf = 0; nf < 4; ++nf) { s[nf] = 0.f; s2[nf] = 0.f; }

    STAGE(0, gc0b);
    __syncthreads();   // prologue: tile 0 ready

    #pragma unroll 1
    for (int t = 0; t < 4; ++t) {
        if (t < 3) STAGE((t + 1) & 1, gc0b + ((t + 1) << 4));   // issue next tile's DMA

        const char* lx = (const char*)lxs[t & 1];
        const int gc0 = gc0b + (t << 4);

        f32x4 acc[4][4];
        #pragma unroll
        for (int nf = 0; nf < 4; ++nf) {
            #pragma unroll
            for (int mf = 0; mf < 4; ++mf)
                acc[mf][nf] = bias4;
        }

        // K-loop: FULLY UNROLLED, pure {ds_read x4 -> MFMA x16}; B all in registers.
        #pragma unroll
        for (int th = 0; th < 18; ++th) {
            const int tt = th >> 1;
            const int h  = th & 1;
            const int dy = (tt * 11) >> 5;   // tt/3
            const int dx = tt - dy * 3;
            const int chunkx = ((h << 2) + qg) ^ ((colbase + dx) & 7);
            bf16x8 a[4];
            #pragma unroll
            for (int mf = 0; mf < 4; ++mf)
                a[mf] = *(const bf16x8*)(lx +
                         abase[mf] + dx * 2304 + dy * 128 + (chunkx << 4));
            #pragma unroll
            for (int mf = 0; mf < 4; ++mf) {
                #pragma unroll
                for (int nf = 0; nf < 4; ++nf)
                    acc[mf][nf] = __builtin_amdgcn_mfma_f32_16x16x32_bf16(
                        breg[th * 4 + nf], a[mf], acc[mf][nf], 0, 0, 0);   // D^T
            }
        }

        // epilogue: lane holds couts {wh*64 + nf*16 + qg*4 .. +3} at pixel p(p15) per mf
        #pragma unroll
        for (int mf = 0; mf < 4; ++mf) {
            int gr = gr0 + wr0 + (mf << 1) + (p15 >> 3);
            int gc = gc0 + wc0 + (p15 & 7);
            unsigned short* op = yb + (((gr << 9) + gc) << 7) + (wh << 6) + (qg << 2);
            #pragma unroll
            for (int nf = 0; nf < 4; ++nf) {
                f32x4 v = acc[mf][nf];
                ushort4 o;
                o.x = f2bf(v[0]); o.y = f2bf(v[1]); o.z = f2bf(v[2]); o.w = f2bf(v[3]);
                *(ushort4*)(op + (nf << 4)) = o;
                s[nf]  += v[0] + v[1] + v[2] + v[3];
                s2[nf] += v[0] * v[0] + v[1] * v[1] + v[2] * v[2] + v[3] * v[3];
            }
        }

        __syncthreads();   // drains next tile's DMA + releases buf[t&1]
    }

    // block-level GN partials (once, after all 4 tiles)
    #pragma unroll
    for (int nf = 0; nf < 4; ++nf) {
        s[nf]  += __shfl_xor(s[nf], 1);  s[nf]  += __shfl_xor(s[nf], 2);
        s[nf]  += __shfl_xor(s[nf], 4);  s[nf]  += __shfl_xor(s[nf], 8);
        s2[nf] += __shfl_xor(s2[nf], 1); s2[nf] += __shfl_xor(s2[nf], 2);
        s2[nf] += __shfl_xor(s2[nf], 4); s2[nf] += __shfl_xor(s2[nf], 8);
    }
    if (p15 == 0) {
        #pragma unroll
        for (int nf = 0; nf < 4; ++nf) {
            sred[w][(nf << 2) + qg]      = s[nf];
            sred[w][16 + (nf << 2) + qg] = s2[nf];
        }
    }
    __syncthreads();
    if (tid < 64) {
        int isS2 = tid >> 5;         // 0: sums, 1: sumsqs
        int g    = tid & 31;         // global group
        int gh   = g >> 4;           // which cout half
        int g16  = (g & 15) + (isS2 << 4);
        float v = sred[(gh << 2) + 0][g16] + sred[(gh << 2) + 1][g16]
                + sred[(gh << 2) + 2][g16] + sred[(gh << 2) + 3][g16];
        part[(blockIdx.x << 6) + (isS2 << 5) + g] = v;
    }
}

// K3: reduce 256 block partials -> mu[g], inv_std[g]
__global__ void k_final(const float* __restrict__ part, float* __restrict__ params) {
    __shared__ float sh[256];
    int t = threadIdx.x;
    int col = t & 63, q = t >> 6;
    float s = 0.f;
    for (int r = q; r < 256; r += 4) s += part[r * 64 + col];
    sh[t] = s;
    __syncthreads();
    if (t < 64) sh[t] = sh[t] + sh[64 + t] + sh[128 + t] + sh[192 + t];
    __syncthreads();
    if (t < 32) {
        const float invN = 1.0f / (512.0f * 512.0f * 4.0f);
        float mu  = sh[t] * invN;
        float var = sh[32 + t] * invN - mu * mu;
        params[t]      = mu;
        params[32 + t] = rsqrtf(var + 1e-5f);
    }
}

// K4: normalize + scale/bias + tanh-GELU; read bf16 y from ws, write f32 to d_out.
__global__ void k_gelu(const unsigned short* __restrict__ yb, float* __restrict__ out,
                       const float* __restrict__ params, const float* __restrict__ scale,
                       const float* __restrict__ bias) {
    int t = blockIdx.x * 256 + threadIdx.x;   // 4,194,304 threads, 8 channels each
    int c0 = (t & 15) << 3;
    uint4 raw = ((const uint4*)yb)[t];
    unsigned us[8];
    us[0] = raw.x & 0xffffu; us[1] = raw.x >> 16;
    us[2] = raw.y & 0xffffu; us[3] = raw.y >> 16;
    us[4] = raw.z & 0xffffu; us[5] = raw.z >> 16;
    us[6] = raw.w & 0xffffu; us[7] = raw.w >> 16;
    int g0 = c0 >> 2;
    float mu0 = params[g0],     iv0 = params[32 + g0];
    float mu1 = params[g0 + 1], iv1 = params[33 + g0];
    float scb[8], bib[8];
    *(float4*)&scb[0] = *(const float4*)&scale[c0];
    *(float4*)&scb[4] = *(const float4*)&scale[c0 + 4];
    *(float4*)&bib[0] = *(const float4*)&bias[c0];
    *(float4*)&bib[4] = *(const float4*)&bias[c0 + 4];
    float o[8];
    #pragma unroll
    for (int k = 0; k < 8; ++k) {
        float xf = __uint_as_float(us[k] << 16);
        float mu = (k < 4) ? mu0 : mu1;
        float iv = (k < 4) ? iv0 : iv1;
        float z  = (xf - mu) * iv * scb[k] + bib[k];
        float a  = 0.7978845608028654f * (z + 0.044715f * z * z * z);
        o[k] = z / (1.0f + __expf(-2.0f * a));
    }
    float4* op = (float4*)(out + ((size_t)t << 3));
    op[0] = make_float4(o[0], o[1], o[2], o[3]);
    op[1] = make_float4(o[4], o[5], o[6], o[7]);
}

extern "C" void kernel_launch(void* const* d_in, const int* in_sizes, int n_in,
                              void* d_out, int out_size, void* d_ws, size_t ws_size,
                              hipStream_t stream) {
    const float* x  = (const float*)d_in[0];
    const float* W1 = (const float*)d_in[1];
    const float* b1 = (const float*)d_in[2];
    const float* W2 = (const float*)d_in[3];
    const float* b2 = (const float*)d_in[4];
    const float* gs = (const float*)d_in[5];
    const float* gb = (const float*)d_in[6];
    float* out = (float*)d_out;

    char* ws = (char*)d_ws;
    unsigned short* xd    = (unsigned short*)d_out;   // xd lives in d_out, dead before k_gelu
    unsigned short* yb    = (unsigned short*)(ws);
    unsigned short* Bpk   = (unsigned short*)(ws + 67108864);
    float* bf             = (float*)(ws + 67256320);
    float* part           = (float*)(ws + 67256832);
    float* params         = (float*)(ws + 67322368);
    unsigned short* zeroz = (unsigned short*)(ws + 67519232);

    k_prep<<<8192 + 289, 256, 0, stream>>>(x, W1, b1, W2, b2, xd, Bpk, bf, zeroz);
    k_conv<<<256, 512, 0, stream>>>(xd, Bpk, bf, zeroz, yb, part);
    k_final<<<1, 256, 0, stream>>>(part, params);
    k_gelu<<<(HO * WO * COUT / 8) / 256, 256, 0, stream>>>(yb, out, params, gs, gb);
}

// Round 17
// 185.897 us; speedup vs baseline: 1.6786x; 1.6786x over previous
//
#include <hip/hip_runtime.h>
#include <math.h>

// Problem constants
#define HI 1024
#define WI 1024
#define HO 512
#define WO 512
#define CIN 64
#define COUT 128
#define NW (9*CIN*COUT)   // 73728 fused 3x3 weights

typedef __attribute__((ext_vector_type(8))) short bf16x8;
typedef __attribute__((ext_vector_type(4))) float f32x4;

// Buffer plan:
//   d_out[0 .. 33.5MB) : xd, TRANSPOSED layout: px(gr,gc) at ((gc*512+gr)*64+c)
//                        -- dead before k_gelu overwrites d_out
//   ws layout (bytes):
//     yb     : 0         .. 67108864   (512*512*128 bf16 conv output)
//     Bpk    : 67108864  .. 67256320   (9*2*8*64*8 bf16, MFMA-fragment order)
//     bf     : 67256320  .. 67256832   (128 f32 fused bias)
//     part   : 67256832  .. 67387904   (512 blocks * 64 f32 partials)
//     params : 67387904  .. 67388160   (mu[32], inv_std[32])
//     zeroz  : 67519232  .. 67519360   (128B zeros for OOB halo DMA source)

#define GLDS(g, l) __builtin_amdgcn_global_load_lds( \
    (const __attribute__((address_space(1))) void*)(g), \
    (__attribute__((address_space(3))) void*)(l), 16, 0, 0)

__device__ __forceinline__ unsigned short f2bf(float f) {   // round-to-nearest-even
    unsigned u = __float_as_uint(f);
    u += 0x7fffu + ((u >> 16) & 1u);
    return (unsigned short)(u >> 16);
}

// K1: merged prep kernel (R14-proven). Blocks [0,8192): bilinear downsample
// (reference's transposed sampling: out px (i,j) samples x(row=j*step, col=i*step),
// OOB zero-fill); i fast -> streaming reads; transposed xd -> contiguous writes.
// Blocks [8192,8481): weight fold+pack, bias fold, zero scratch.
__global__ void k_prep(const float* __restrict__ x,
                       const float* __restrict__ W1, const float* __restrict__ b1,
                       const float* __restrict__ W2, const float* __restrict__ b2,
                       unsigned short* __restrict__ xd,
                       unsigned short* __restrict__ Bpk, float* __restrict__ bf,
                       unsigned short* __restrict__ zeroz) {
    int bid = blockIdx.x;
    if (bid < 8192) {
        int t = bid * 256 + threadIdx.x;   // 2,097,152 threads, 8 channels each
        int c8 = t & 7;
        int i  = (t >> 3) & (WO - 1);      // FAST: x column coordinate source
        int j  = t >> 12;                  // slow: x row coordinate source
        const float step = 1024.0f / 511.0f;
        float tr = (float)j * step;        // x row coordinate (transposed sampling!)
        float tc = (float)i * step;        // x col coordinate
        int r0 = (int)tr; float fr = tr - (float)r0;
        int c0 = (int)tc; float fc = tc - (float)c0;
        float w00 = (1.f - fr) * (1.f - fc);
        float w01 = (1.f - fr) * fc;
        float w10 = fr * (1.f - fc);
        float w11 = fr * fc;
        float a0 = 0.f, a1 = 0.f, a2 = 0.f, a3 = 0.f;
        float a4 = 0.f, a5 = 0.f, a6 = 0.f, a7 = 0.f;
        const float* xb = x + (c8 << 3);
        #define TAP(R, C, W) \
            if ((R) < HI && (C) < WI) { \
                const float* p = xb + ((((R) << 10) + (C)) << 6); \
                float4 v0 = *(const float4*)p; \
                float4 v1 = *(const float4*)(p + 4); \
                a0 += (W) * v0.x; a1 += (W) * v0.y; a2 += (W) * v0.z; a3 += (W) * v0.w; \
                a4 += (W) * v1.x; a5 += (W) * v1.y; a6 += (W) * v1.z; a7 += (W) * v1.w; \
            }
        TAP(r0,     c0,     w00)
        TAP(r0,     c0 + 1, w01)
        TAP(r0 + 1, c0,     w10)
        TAP(r0 + 1, c0 + 1, w11)
        #undef TAP
        uint4 pk;
        pk.x = (unsigned)f2bf(a0) | ((unsigned)f2bf(a1) << 16);
        pk.y = (unsigned)f2bf(a2) | ((unsigned)f2bf(a3) << 16);
        pk.z = (unsigned)f2bf(a4) | ((unsigned)f2bf(a5) << 16);
        pk.w = (unsigned)f2bf(a6) | ((unsigned)f2bf(a7) << 16);
        // TRANSPOSED store: px (i,j) -> ((j*512 + i)*64 + c8*8); contiguous in i
        *(uint4*)&xd[(((j << 9) + i) << 6) + (c8 << 3)] = pk;
    } else {
        int idx = (bid - 8192) * 256 + threadIdx.x;
        if (idx < NW) {
            int j  = idx & 7;
            int l  = (idx >> 3) & 63;
            int nf = (idx >> 9) & 7;
            int h  = (idx >> 12) & 1;
            int t  = idx >> 13;
            int cin  = (h << 5) + ((l >> 4) << 3) + j;
            int cout = (nf << 4) + (l & 15);
            float v = W1[(t * 64 + cin) * 128 + cout];
            if (t == 4) v += W2[cin * 128 + cout];   // center tap gets the 1x1 conv
            Bpk[idx] = f2bf(v);
        } else if (idx < NW + COUT) {
            int c = idx - NW;
            bf[c] = b1[c] + b2[c];
        } else if (idx < NW + COUT + 64) {
            zeroz[idx - NW - COUT] = 0;
        }
    }
}

// K2: persistent double-buffered MFMA conv, 2 BLOCKS PER CU (two independent
// barrier domains -> cross-block overlap hides the DMA-drain barrier, m114).
// 512 blocks x 256 threads (4 waves: 2 px-row-halves x 2 cout-halves), tile
// 16x8 px, halo 18 rows x 10 cols col-major (23KB/buffer, 46KB dbuf).
// Per-wave micro-structure identical to R13: 4 ds_read -> 16 MFMA, 1-tap B
// prefetch, XOR chunk swizzle. 4 tiles per block along a row.
__global__ __launch_bounds__(256, 2) void k_conv(
        const unsigned short* __restrict__ xd,
        const unsigned short* __restrict__ Bpk,
        const float* __restrict__ bf,
        const unsigned short* __restrict__ zeroz,
        unsigned short* __restrict__ yb, float* __restrict__ part) {
    __shared__ short lxs[2][180 * 64];     // 2 x (10 cols x 18 rows) x 64cin bf16 (46080 B)
    __shared__ float sred[4][32];

    const int tid = threadIdx.x;
    const int l   = tid & 63;
    const int w   = tid >> 6;              // 4 waves
    const int trow = blockIdx.x >> 4;      // 32 tile-rows (16 px each)
    const int tcs  = blockIdx.x & 15;      // 16 col-spans (32 cols each)
    const int gr0  = trow << 4;
    const int gc0b = tcs << 5;             // first tile's gc0 (4 tiles x 8 cols)

    const int wh  = w >> 1;                // cout half
    const int wr0 = (w & 1) << 3;          // px row half: 0 or 8
    const int qg  = l >> 4;
    const int p15 = l & 15;
    const int colbase = l & 7;             // tile col 0..7
    // A-read base per mf in the [col][row] halo (col stride 18 rows x 128B):
    int abase[4];
    #pragma unroll
    for (int mf = 0; mf < 4; ++mf)
        abase[mf] = (colbase * 18 + wr0 + 2 * mf + (p15 >> 3)) * 128;

    const bf16x8* Bbase = (const bf16x8*)Bpk;
    // tap-0 B fragments: loaded once, resident across all 4 tiles
    bf16x8 b0[4];
    #pragma unroll
    for (int nf = 0; nf < 4; ++nf)
        b0[nf] = Bbase[(((wh << 2) + nf) << 6) + l];
    f32x4 bias4 = *(const f32x4*)&bf[(wh << 6) + (qg << 2)];

    auto STAGE = [&](int bufi, int gc0t) {
        #pragma unroll
        for (int k = 0; k < 6; ++k) {
            int idx = tid + (k << 8);
            if (idx < 180 * 8) {
                int pos = idx >> 3, c = idx & 7;
                int col = (pos * 57) >> 10;            // pos/18 for pos<180
                int row = pos - col * 18;
                int gr = gr0 + row - 1, gc = gc0t + col - 1;
                bool inpx = (gr >= 0) && (gr < HO) && (gc >= 0) && (gc < WO);
                // transposed xd: px(gr,gc) at ((gc*512+gr)*64); consecutive row -> +128B
                const unsigned short* src = inpx
                    ? xd + (((gc << 9) + gr) << 6) + ((c ^ (col & 7)) << 3)
                    : zeroz;
                GLDS(src, (char*)lxs[bufi] + (((k << 8) + (w << 6)) << 4));
            }
        }
    };

    float s[4], s2[4];
    #pragma unroll
    for (int nf = 0; nf < 4; ++nf) { s[nf] = 0.f; s2[nf] = 0.f; }

    STAGE(0, gc0b);
    __syncthreads();   // prologue: tile 0 ready

    #pragma unroll 1
    for (int t = 0; t < 4; ++t) {
        if (t < 3) STAGE((t + 1) & 1, gc0b + ((t + 1) << 3));   // issue next tile's DMA

        const char* lx = (const char*)lxs[t & 1];
        const int gc0 = gc0b + (t << 3);

        f32x4 acc[4][4];
        #pragma unroll
        for (int nf = 0; nf < 4; ++nf) {
            #pragma unroll
            for (int mf = 0; mf < 4; ++mf)
                acc[mf][nf] = bias4;
        }

        bf16x8 bcur[4];
        #pragma unroll
        for (int nf = 0; nf < 4; ++nf) bcur[nf] = b0[nf];

        #pragma unroll 1
        for (int th = 0; th < 18; ++th) {
            const int thn = (th < 17) ? th + 1 : 0;
            bf16x8 bnxt[4];
            {
                const bf16x8* Bth = Bbase + (thn << 9);
                #pragma unroll
                for (int nf = 0; nf < 4; ++nf)
                    bnxt[nf] = Bth[(((wh << 2) + nf) << 6) + l];
            }
            const int tt = th >> 1;
            const int h  = th & 1;
            const int dy = (tt * 11) >> 5;   // tt/3
            const int dx = tt - dy * 3;
            const int chunkx = ((h << 2) + qg) ^ ((colbase + dx) & 7);
            bf16x8 a[4];
            #pragma unroll
            for (int mf = 0; mf < 4; ++mf)
                a[mf] = *(const bf16x8*)(lx +
                         abase[mf] + dx * 2304 + dy * 128 + (chunkx << 4));
            #pragma unroll
            for (int mf = 0; mf < 4; ++mf) {
                #pragma unroll
                for (int nf = 0; nf < 4; ++nf)
                    acc[mf][nf] = __builtin_amdgcn_mfma_f32_16x16x32_bf16(
                        bcur[nf], a[mf], acc[mf][nf], 0, 0, 0);   // D^T: rows=cout, cols=px
            }
            #pragma unroll
            for (int nf = 0; nf < 4; ++nf)
                bcur[nf] = bnxt[nf];
        }

        // epilogue: lane holds couts {wh*64 + nf*16 + qg*4 .. +3} at pixel p(p15) per mf
        #pragma unroll
        for (int mf = 0; mf < 4; ++mf) {
            int gr = gr0 + wr0 + (mf << 1) + (p15 >> 3);
            int gc = gc0 + (p15 & 7);
            unsigned short* op = yb + (((gr << 9) + gc) << 7) + (wh << 6) + (qg << 2);
            #pragma unroll
            for (int nf = 0; nf < 4; ++nf) {
                f32x4 v = acc[mf][nf];
                ushort4 o;
                o.x = f2bf(v[0]); o.y = f2bf(v[1]); o.z = f2bf(v[2]); o.w = f2bf(v[3]);
                *(ushort4*)(op + (nf << 4)) = o;
                s[nf]  += v[0] + v[1] + v[2] + v[3];
                s2[nf] += v[0] * v[0] + v[1] * v[1] + v[2] * v[2] + v[3] * v[3];
            }
        }

        __syncthreads();   // drains next tile's DMA + releases buf[t&1]
    }

    // block-level GN partials (once, after all 4 tiles)
    #pragma unroll
    for (int nf = 0; nf < 4; ++nf) {
        s[nf]  += __shfl_xor(s[nf], 1);  s[nf]  += __shfl_xor(s[nf], 2);
        s[nf]  += __shfl_xor(s[nf], 4);  s[nf]  += __shfl_xor(s[nf], 8);
        s2[nf] += __shfl_xor(s2[nf], 1); s2[nf] += __shfl_xor(s2[nf], 2);
        s2[nf] += __shfl_xor(s2[nf], 4); s2[nf] += __shfl_xor(s2[nf], 8);
    }
    if (p15 == 0) {
        #pragma unroll
        for (int nf = 0; nf < 4; ++nf) {
            sred[w][(nf << 2) + qg]      = s[nf];
            sred[w][16 + (nf << 2) + qg] = s2[nf];
        }
    }
    __syncthreads();
    if (tid < 64) {
        int isS2 = tid >> 5;         // 0: sums, 1: sumsqs
        int g    = tid & 31;         // global group
        int gh   = g >> 4;           // cout half -> waves {2gh, 2gh+1}
        int g16  = (g & 15) + (isS2 << 4);
        float v = sred[(gh << 1)][g16] + sred[(gh << 1) + 1][g16];
        part[(blockIdx.x << 6) + (isS2 << 5) + g] = v;
    }
}

// K3: reduce 512 block partials -> mu[g], inv_std[g]
__global__ void k_final(const float* __restrict__ part, float* __restrict__ params) {
    __shared__ float sh[256];
    int t = threadIdx.x;
    int col = t & 63, q = t >> 6;
    float s = 0.f;
    for (int r = q; r < 512; r += 4) s += part[r * 64 + col];
    sh[t] = s;
    __syncthreads();
    if (t < 64) sh[t] = sh[t] + sh[64 + t] + sh[128 + t] + sh[192 + t];
    __syncthreads();
    if (t < 32) {
        const float invN = 1.0f / (512.0f * 512.0f * 4.0f);
        float mu  = sh[t] * invN;
        float var = sh[32 + t] * invN - mu * mu;
        params[t]      = mu;
        params[32 + t] = rsqrtf(var + 1e-5f);
    }
}

// K4: normalize + scale/bias + tanh-GELU; read bf16 y from ws, write f32 to d_out.
__global__ void k_gelu(const unsigned short* __restrict__ yb, float* __restrict__ out,
                       const float* __restrict__ params, const float* __restrict__ scale,
                       const float* __restrict__ bias) {
    int t = blockIdx.x * 256 + threadIdx.x;   // 4,194,304 threads, 8 channels each
    int c0 = (t & 15) << 3;
    uint4 raw = ((const uint4*)yb)[t];
    unsigned us[8];
    us[0] = raw.x & 0xffffu; us[1] = raw.x >> 16;
    us[2] = raw.y & 0xffffu; us[3] = raw.y >> 16;
    us[4] = raw.z & 0xffffu; us[5] = raw.z >> 16;
    us[6] = raw.w & 0xffffu; us[7] = raw.w >> 16;
    int g0 = c0 >> 2;
    float mu0 = params[g0],     iv0 = params[32 + g0];
    float mu1 = params[g0 + 1], iv1 = params[33 + g0];
    float scb[8], bib[8];
    *(float4*)&scb[0] = *(const float4*)&scale[c0];
    *(float4*)&scb[4] = *(const float4*)&scale[c0 + 4];
    *(float4*)&bib[0] = *(const float4*)&bias[c0];
    *(float4*)&bib[4] = *(const float4*)&bias[c0 + 4];
    float o[8];
    #pragma unroll
    for (int k = 0; k < 8; ++k) {
        float xf = __uint_as_float(us[k] << 16);
        float mu = (k < 4) ? mu0 : mu1;
        float iv = (k < 4) ? iv0 : iv1;
        float z  = (xf - mu) * iv * scb[k] + bib[k];
        float a  = 0.7978845608028654f * (z + 0.044715f * z * z * z);
        o[k] = z / (1.0f + __expf(-2.0f * a));
    }
    float4* op = (float4*)(out + ((size_t)t << 3));
    op[0] = make_float4(o[0], o[1], o[2], o[3]);
    op[1] = make_float4(o[4], o[5], o[6], o[7]);
}

extern "C" void kernel_launch(void* const* d_in, const int* in_sizes, int n_in,
                              void* d_out, int out_size, void* d_ws, size_t ws_size,
                              hipStream_t stream) {
    const float* x  = (const float*)d_in[0];
    const float* W1 = (const float*)d_in[1];
    const float* b1 = (const float*)d_in[2];
    const float* W2 = (const float*)d_in[3];
    const float* b2 = (const float*)d_in[4];
    const float* gs = (const float*)d_in[5];
    const float* gb = (const float*)d_in[6];
    float* out = (float*)d_out;

    char* ws = (char*)d_ws;
    unsigned short* xd    = (unsigned short*)d_out;   // xd lives in d_out, dead before k_gelu
    unsigned short* yb    = (unsigned short*)(ws);
    unsigned short* Bpk   = (unsigned short*)(ws + 67108864);
    float* bf             = (float*)(ws + 67256320);
    float* part           = (float*)(ws + 67256832);
    float* params         = (float*)(ws + 67387904);
    unsigned short* zeroz = (unsigned short*)(ws + 67519232);

    k_prep<<<8192 + 289, 256, 0, stream>>>(x, W1, b1, W2, b2, xd, Bpk, bf, zeroz);
    k_conv<<<512, 256, 0, stream>>>(xd, Bpk, bf, zeroz, yb, part);
    k_final<<<1, 256, 0, stream>>>(part, params);
    k_gelu<<<(HO * WO * COUT / 8) / 256, 256, 0, stream>>>(yb, out, params, gs, gb);
}

// Round 18
// 182.214 us; speedup vs baseline: 1.7126x; 1.0202x over previous
//
#include <hip/hip_runtime.h>
#include <math.h>

// Problem constants
#define HI 1024
#define WI 1024
#define HO 512
#define WO 512
#define CIN 64
#define COUT 128
#define NW (9*CIN*COUT)   // 73728 fused 3x3 weights

typedef __attribute__((ext_vector_type(8))) short bf16x8;
typedef __attribute__((ext_vector_type(4))) float f32x4;

// Buffer plan:
//   d_out[0 .. 33.5MB) : xd, TRANSPOSED layout: px(gr,gc) at ((gc*512+gr)*64+c)
//                        -- dead before k_gelu overwrites d_out
//   ws layout (bytes):
//     yb     : 0         .. 67108864   (512*512*128 bf16 conv output)
//     Bpk    : 67108864  .. 67256320   (9*2*8*64*8 bf16, MFMA-fragment order)
//     bf     : 67256320  .. 67256832   (128 f32 fused bias)
//     part   : 67256832  .. 67322368   (256 blocks * 64 f32 partials)
//     params : 67322368  .. 67322624   (mu[32], inv_std[32])
//     ctr    : 67322624  .. 67322628   (conv done-counter, re-zeroed each call)
//     zeroz  : 67519232  .. 67519360   (128B zeros for OOB halo DMA source)

#define GLDS(g, l) __builtin_amdgcn_global_load_lds( \
    (const __attribute__((address_space(1))) void*)(g), \
    (__attribute__((address_space(3))) void*)(l), 16, 0, 0)

__device__ __forceinline__ unsigned short f2bf(float f) {   // round-to-nearest-even
    unsigned u = __float_as_uint(f);
    u += 0x7fffu + ((u >> 16) & 1u);
    return (unsigned short)(u >> 16);
}

// K1: merged prep kernel (R13/R14-proven). Blocks [0,8192): bilinear downsample
// (reference's transposed sampling: out px (i,j) samples x(row=j*step, col=i*step),
// OOB zero-fill); i fast -> streaming reads; transposed xd -> contiguous writes.
// Blocks [8192,8481): weight fold+pack, bias fold, zero scratch + done-counter.
__global__ void k_prep(const float* __restrict__ x,
                       const float* __restrict__ W1, const float* __restrict__ b1,
                       const float* __restrict__ W2, const float* __restrict__ b2,
                       unsigned short* __restrict__ xd,
                       unsigned short* __restrict__ Bpk, float* __restrict__ bf,
                       unsigned short* __restrict__ zeroz, unsigned* __restrict__ ctr) {
    int bid = blockIdx.x;
    if (bid < 8192) {
        int t = bid * 256 + threadIdx.x;   // 2,097,152 threads, 8 channels each
        int c8 = t & 7;
        int i  = (t >> 3) & (WO - 1);      // FAST: x column coordinate source
        int j  = t >> 12;                  // slow: x row coordinate source
        const float step = 1024.0f / 511.0f;
        float tr = (float)j * step;        // x row coordinate (transposed sampling!)
        float tc = (float)i * step;        // x col coordinate
        int r0 = (int)tr; float fr = tr - (float)r0;
        int c0 = (int)tc; float fc = tc - (float)c0;
        float w00 = (1.f - fr) * (1.f - fc);
        float w01 = (1.f - fr) * fc;
        float w10 = fr * (1.f - fc);
        float w11 = fr * fc;
        float a0 = 0.f, a1 = 0.f, a2 = 0.f, a3 = 0.f;
        float a4 = 0.f, a5 = 0.f, a6 = 0.f, a7 = 0.f;
        const float* xb = x + (c8 << 3);
        #define TAP(R, C, W) \
            if ((R) < HI && (C) < WI) { \
                const float* p = xb + ((((R) << 10) + (C)) << 6); \
                float4 v0 = *(const float4*)p; \
                float4 v1 = *(const float4*)(p + 4); \
                a0 += (W) * v0.x; a1 += (W) * v0.y; a2 += (W) * v0.z; a3 += (W) * v0.w; \
                a4 += (W) * v1.x; a5 += (W) * v1.y; a6 += (W) * v1.z; a7 += (W) * v1.w; \
            }
        TAP(r0,     c0,     w00)
        TAP(r0,     c0 + 1, w01)
        TAP(r0 + 1, c0,     w10)
        TAP(r0 + 1, c0 + 1, w11)
        #undef TAP
        uint4 pk;
        pk.x = (unsigned)f2bf(a0) | ((unsigned)f2bf(a1) << 16);
        pk.y = (unsigned)f2bf(a2) | ((unsigned)f2bf(a3) << 16);
        pk.z = (unsigned)f2bf(a4) | ((unsigned)f2bf(a5) << 16);
        pk.w = (unsigned)f2bf(a6) | ((unsigned)f2bf(a7) << 16);
        // TRANSPOSED store: px (i,j) -> ((j*512 + i)*64 + c8*8); contiguous in i
        *(uint4*)&xd[(((j << 9) + i) << 6) + (c8 << 3)] = pk;
    } else {
        int idx = (bid - 8192) * 256 + threadIdx.x;
        if (idx < NW) {
            int j  = idx & 7;
            int l  = (idx >> 3) & 63;
            int nf = (idx >> 9) & 7;
            int h  = (idx >> 12) & 1;
            int t  = idx >> 13;
            int cin  = (h << 5) + ((l >> 4) << 3) + j;
            int cout = (nf << 4) + (l & 15);
            float v = W1[(t * 64 + cin) * 128 + cout];
            if (t == 4) v += W2[cin * 128 + cout];   // center tap gets the 1x1 conv
            Bpk[idx] = f2bf(v);
        } else if (idx < NW + COUT) {
            int c = idx - NW;
            bf[c] = b1[c] + b2[c];
        } else if (idx < NW + COUT + 64) {
            zeroz[idx - NW - COUT] = 0;
        } else if (idx == NW + COUT + 64) {
            *ctr = 0;                      // reset done-counter every call
        }
    }
}

// K2: persistent double-buffered MFMA conv (R13-proven), adapted to the transposed
// xd layout: halo staged COLUMN-major (pos = col*18 + row; per-column 2304B
// contiguous global runs), LDS tile is [col][row], XOR chunk swizzle keyed by
// tile-col. 256 blocks (1/CU) x 512 threads (8 waves). The LAST block to finish
// also reduces the GN partials -> params (replaces the k_final launch; agent-scope
// loads for cross-XCD visibility, R10-validated pattern).
__global__ __launch_bounds__(512, 2) void k_conv(
        const unsigned short* __restrict__ xd,
        const unsigned short* __restrict__ Bpk,
        const float* __restrict__ bf,
        const unsigned short* __restrict__ zeroz,
        unsigned short* __restrict__ yb, float* part,
        float* __restrict__ params, unsigned* ctr) {
    __shared__ short lxs[2][324 * 64];     // 2 x (18 cols x 18 rows) x 64cin bf16 (82944 B)
    __shared__ float sred[8][32];          // also reused as 256-float scratch for final reduce
    __shared__ unsigned islast;

    const int tid = threadIdx.x;
    const int l   = tid & 63;
    const int w   = tid >> 6;
    const int trow = blockIdx.x >> 3;      // 32 tile-rows
    const int tcq  = blockIdx.x & 7;       // 8 column-quads
    const int gr0  = trow << 4;
    const int gc0b = (tcq << 2) << 4;      // first tile's gc0

    const int wq  = w & 3;                 // px quadrant
    const int wh  = w >> 2;                // cout half
    const int qg  = l >> 4;
    const int p15 = l & 15;
    const int wr0 = (wq >> 1) << 3;
    const int wc0 = (wq & 1) << 3;
    const int colbase = wc0 + (l & 7);
    // A-read base per mf in the [col][row] tile: (colbase*18 + row)*128
    int abase[4];
    #pragma unroll
    for (int mf = 0; mf < 4; ++mf)
        abase[mf] = (colbase * 18 + wr0 + 2 * mf + (p15 >> 3)) * 128;

    const bf16x8* Bbase = (const bf16x8*)Bpk;
    // tap-0 B fragments: loaded once, resident across all 4 tiles
    bf16x8 b0[4];
    #pragma unroll
    for (int nf = 0; nf < 4; ++nf)
        b0[nf] = Bbase[(((wh << 2) + nf) << 6) + l];
    f32x4 bias4 = *(const f32x4*)&bf[(wh << 6) + (qg << 2)];

    auto STAGE = [&](int bufi, int gc0t) {
        #pragma unroll
        for (int k = 0; k < 6; ++k) {
            int idx = tid + (k << 9);
            if (idx < 324 * 8) {
                int pos = idx >> 3, c = idx & 7;
                int col = (pos * 57) >> 10;            // pos/18: halo COLUMN
                int row = pos - col * 18;              // halo row
                int gr = gr0 + row - 1, gc = gc0t + col - 1;
                bool inpx = (gr >= 0) && (gr < HO) && (gc >= 0) && (gc < WO);
                // transposed xd: px(gr,gc) at ((gc*512+gr)*64); consecutive row -> +128B
                const unsigned short* src = inpx
                    ? xd + (((gc << 9) + gr) << 6) + ((c ^ (col & 7)) << 3)
                    : zeroz;
                GLDS(src, (char*)lxs[bufi] + (((w << 6) + (k << 9)) << 4));
            }
        }
    };

    float s[4], s2[4];
    #pragma unroll
    for (int nf = 0; nf < 4; ++nf) { s[nf] = 0.f; s2[nf] = 0.f; }

    STAGE(0, gc0b);
    __syncthreads();   // prologue: tile 0 ready

    #pragma unroll 1
    for (int t = 0; t < 4; ++t) {
        if (t < 3) STAGE((t + 1) & 1, gc0b + ((t + 1) << 4));   // issue next tile's DMA

        const char* lx = (const char*)lxs[t & 1];
        const int gc0 = gc0b + (t << 4);

        f32x4 acc[4][4];
        #pragma unroll
        for (int nf = 0; nf < 4; ++nf) {
            #pragma unroll
            for (int mf = 0; mf < 4; ++mf)
                acc[mf][nf] = bias4;
        }

        bf16x8 bcur[4];
        #pragma unroll
        for (int nf = 0; nf < 4; ++nf) bcur[nf] = b0[nf];

        #pragma unroll 1
        for (int th = 0; th < 18; ++th) {
            const int thn = (th < 17) ? th + 1 : 0;
            bf16x8 bnxt[4];
            {
                const bf16x8* Bth = Bbase + (thn << 9);
                #pragma unroll
                for (int nf = 0; nf < 4; ++nf)
                    bnxt[nf] = Bth[(((wh << 2) + nf) << 6) + l];
            }
            const int tt = th >> 1;
            const int h  = th & 1;
            const int dy = (tt * 11) >> 5;   // tt/3
            const int dx = tt - dy * 3;
            const int chunkx = ((h << 2) + qg) ^ ((colbase + dx) & 7);
            bf16x8 a[4];
            #pragma unroll
            for (int mf = 0; mf < 4; ++mf)
                a[mf] = *(const bf16x8*)(lx +
                         abase[mf] + dx * 2304 + dy * 128 + (chunkx << 4));
            #pragma unroll
            for (int mf = 0; mf < 4; ++mf) {
                #pragma unroll
                for (int nf = 0; nf < 4; ++nf)
                    acc[mf][nf] = __builtin_amdgcn_mfma_f32_16x16x32_bf16(
                        bcur[nf], a[mf], acc[mf][nf], 0, 0, 0);   // D^T: rows=cout, cols=px
            }
            #pragma unroll
            for (int nf = 0; nf < 4; ++nf)
                bcur[nf] = bnxt[nf];
        }

        // epilogue: lane holds couts {wh*64 + nf*16 + qg*4 .. +3} at pixel p(p15) per mf
        #pragma unroll
        for (int mf = 0; mf < 4; ++mf) {
            int gr = gr0 + wr0 + (mf << 1) + (p15 >> 3);
            int gc = gc0 + wc0 + (p15 & 7);
            unsigned short* op = yb + (((gr << 9) + gc) << 7) + (wh << 6) + (qg << 2);
            #pragma unroll
            for (int nf = 0; nf < 4; ++nf) {
                f32x4 v = acc[mf][nf];
                ushort4 o;
                o.x = f2bf(v[0]); o.y = f2bf(v[1]); o.z = f2bf(v[2]); o.w = f2bf(v[3]);
                *(ushort4*)(op + (nf << 4)) = o;
                s[nf]  += v[0] + v[1] + v[2] + v[3];
                s2[nf] += v[0] * v[0] + v[1] * v[1] + v[2] * v[2] + v[3] * v[3];
            }
        }

        __syncthreads();   // drains next tile's DMA + releases buf[t&1]
    }

    // block-level GN partials (once, after all 4 tiles)
    #pragma unroll
    for (int nf = 0; nf < 4; ++nf) {
        s[nf]  += __shfl_xor(s[nf], 1);  s[nf]  += __shfl_xor(s[nf], 2);
        s[nf]  += __shfl_xor(s[nf], 4);  s[nf]  += __shfl_xor(s[nf], 8);
        s2[nf] += __shfl_xor(s2[nf], 1); s2[nf] += __shfl_xor(s2[nf], 2);
        s2[nf] += __shfl_xor(s2[nf], 4); s2[nf] += __shfl_xor(s2[nf], 8);
    }
    if (p15 == 0) {
        #pragma unroll
        for (int nf = 0; nf < 4; ++nf) {
            sred[w][(nf << 2) + qg]      = s[nf];
            sred[w][16 + (nf << 2) + qg] = s2[nf];
        }
    }
    __syncthreads();
    if (tid < 64) {
        int isS2 = tid >> 5;         // 0: sums, 1: sumsqs
        int g    = tid & 31;         // global group
        int gh   = g >> 4;           // which cout half
        int g16  = (g & 15) + (isS2 << 4);
        float v = sred[(gh << 2) + 0][g16] + sred[(gh << 2) + 1][g16]
                + sred[(gh << 2) + 2][g16] + sred[(gh << 2) + 3][g16];
        part[(blockIdx.x << 6) + (isS2 << 5) + g] = v;
        __threadfence();             // release: this block's partials device-visible
    }
    __syncthreads();                 // order tid0's counter bump after all part writes
    if (tid == 0) islast = (atomicAdd(ctr, 1u) == 255u) ? 1u : 0u;
    __syncthreads();

    // ---- last block only: reduce 256 x 64 partials -> mu[g], inv_std[g] ----
    if (islast) {
        float* fin = &sred[0][0];    // reuse 256-float LDS scratch
        if (tid < 256) {
            int col = tid & 63, q = tid >> 6;
            float ps = 0.f;
            for (int r = q; r < 256; r += 4)
                ps += __hip_atomic_load(&part[r * 64 + col], __ATOMIC_RELAXED,
                                        __HIP_MEMORY_SCOPE_AGENT);
            fin[tid] = ps;
        }
        __syncthreads();
        if (tid < 64) fin[tid] = fin[tid] + fin[64 + tid] + fin[128 + tid] + fin[192 + tid];
        __syncthreads();
        if (tid < 32) {
            const float invN = 1.0f / (512.0f * 512.0f * 4.0f);
            float mu  = fin[tid] * invN;
            float var = fin[32 + tid] * invN - mu * mu;
            params[tid]      = mu;
            params[32 + tid] = rsqrtf(var + 1e-5f);
        }
    }
}

// K3: normalize + scale/bias + tanh-GELU; read bf16 y from ws, write f32 to d_out.
__global__ void k_gelu(const unsigned short* __restrict__ yb, float* __restrict__ out,
                       const float* __restrict__ params, const float* __restrict__ scale,
                       const float* __restrict__ bias) {
    int t = blockIdx.x * 256 + threadIdx.x;   // 4,194,304 threads, 8 channels each
    int c0 = (t & 15) << 3;
    uint4 raw = ((const uint4*)yb)[t];
    unsigned us[8];
    us[0] = raw.x & 0xffffu; us[1] = raw.x >> 16;
    us[2] = raw.y & 0xffffu; us[3] = raw.y >> 16;
    us[4] = raw.z & 0xffffu; us[5] = raw.z >> 16;
    us[6] = raw.w & 0xffffu; us[7] = raw.w >> 16;
    int g0 = c0 >> 2;
    float mu0 = params[g0],     iv0 = params[32 + g0];
    float mu1 = params[g0 + 1], iv1 = params[33 + g0];
    float scb[8], bib[8];
    *(float4*)&scb[0] = *(const float4*)&scale[c0];
    *(float4*)&scb[4] = *(const float4*)&scale[c0 + 4];
    *(float4*)&bib[0] = *(const float4*)&bias[c0];
    *(float4*)&bib[4] = *(const float4*)&bias[c0 + 4];
    float o[8];
    #pragma unroll
    for (int k = 0; k < 8; ++k) {
        float xf = __uint_as_float(us[k] << 16);
        float mu = (k < 4) ? mu0 : mu1;
        float iv = (k < 4) ? iv0 : iv1;
        float z  = (xf - mu) * iv * scb[k] + bib[k];
        float a  = 0.7978845608028654f * (z + 0.044715f * z * z * z);
        o[k] = z / (1.0f + __expf(-2.0f * a));
    }
    float4* op = (float4*)(out + ((size_t)t << 3));
    op[0] = make_float4(o[0], o[1], o[2], o[3]);
    op[1] = make_float4(o[4], o[5], o[6], o[7]);
}

extern "C" void kernel_launch(void* const* d_in, const int* in_sizes, int n_in,
                              void* d_out, int out_size, void* d_ws, size_t ws_size,
                              hipStream_t stream) {
    const float* x  = (const float*)d_in[0];
    const float* W1 = (const float*)d_in[1];
    const float* b1 = (const float*)d_in[2];
    const float* W2 = (const float*)d_in[3];
    const float* b2 = (const float*)d_in[4];
    const float* gs = (const float*)d_in[5];
    const float* gb = (const float*)d_in[6];
    float* out = (float*)d_out;

    char* ws = (char*)d_ws;
    unsigned short* xd    = (unsigned short*)d_out;   // xd lives in d_out, dead before k_gelu
    unsigned short* yb    = (unsigned short*)(ws);
    unsigned short* Bpk   = (unsigned short*)(ws + 67108864);
    float* bf             = (float*)(ws + 67256320);
    float* part           = (float*)(ws + 67256832);
    float* params         = (float*)(ws + 67322368);
    unsigned* ctr         = (unsigned*)(ws + 67322624);
    unsigned short* zeroz = (unsigned short*)(ws + 67519232);

    k_prep<<<8192 + 289, 256, 0, stream>>>(x, W1, b1, W2, b2, xd, Bpk, bf, zeroz, ctr);
    k_conv<<<256, 512, 0, stream>>>(xd, Bpk, bf, zeroz, yb, part, params, ctr);
    k_gelu<<<(HO * WO * COUT / 8) / 256, 256, 0, stream>>>(yb, out, params, gs, gb);
}

// Round 19
// 172.975 us; speedup vs baseline: 1.8040x; 1.0534x over previous
//
#include <hip/hip_runtime.h>
#include <math.h>

// Problem constants
#define HI 1024
#define WI 1024
#define HO 512
#define WO 512
#define CIN 64
#define COUT 128
#define NW (9*CIN*COUT)   // 73728 fused 3x3 weights

typedef __attribute__((ext_vector_type(8))) short bf16x8;
typedef __attribute__((ext_vector_type(4))) float f32x4;

// Buffer plan:
//   d_out[0 .. 33.5MB) : xd (512*512*64 bf16) -- dead before k_gelu overwrites d_out
//   ws layout (bytes):
//     yb     : 0         .. 67108864   (512*512*128 bf16 conv output)
//     Bpk    : 67108864  .. 67256320   (9*2*8*64*8 bf16, MFMA-fragment order)
//     bf     : 67256320  .. 67256832   (128 f32 fused bias)
//     part   : 67256832  .. 67322368   (256 blocks * 64 f32 partials)
//     params : 67322368  .. 67322624   (mu[32], inv_std[32])
//     zeroz  : 67519232  .. 67519360   (128B zeros for OOB halo DMA source)

#define GLDS(g, l) __builtin_amdgcn_global_load_lds( \
    (const __attribute__((address_space(1))) void*)(g), \
    (__attribute__((address_space(3))) void*)(l), 16, 0, 0)

__device__ __forceinline__ unsigned short f2bf(float f) {   // round-to-nearest-even
    unsigned u = __float_as_uint(f);
    u += 0x7fffu + ((u >> 16) & 1u);
    return (unsigned short)(u >> 16);
}

// K1: merged prep kernel. Blocks [0,8192): bilinear downsample (reference's
// transposed sampling: xd[i][j] = x(row=j*step, col=i*step), OOB zero-fill).
// Thread mapping: i FAST (streams x columns -> contiguous reads along 2 x-rows
// per wave), j slow. Writes scatter at 32KB stride (8x smaller than reads).
// Blocks [8192,8481): weight fold+pack, bias fold, zero scratch.
__global__ void k_prep(const float* __restrict__ x,
                       const float* __restrict__ W1, const float* __restrict__ b1,
                       const float* __restrict__ W2, const float* __restrict__ b2,
                       unsigned short* __restrict__ xd,
                       unsigned short* __restrict__ Bpk, float* __restrict__ bf,
                       unsigned short* __restrict__ zeroz) {
    int bid = blockIdx.x;
    if (bid < 8192) {
        int t = bid * 256 + threadIdx.x;   // 2,097,152 threads, 8 channels each
        int c8 = t & 7;
        int i  = (t >> 3) & (WO - 1);      // FAST: x column coordinate source
        int j  = t >> 12;                  // slow: x row coordinate source
        const float step = 1024.0f / 511.0f;
        float tr = (float)j * step;        // x row coordinate (transposed sampling!)
        float tc = (float)i * step;        // x col coordinate
        int r0 = (int)tr; float fr = tr - (float)r0;
        int c0 = (int)tc; float fc = tc - (float)c0;
        float w00 = (1.f - fr) * (1.f - fc);
        float w01 = (1.f - fr) * fc;
        float w10 = fr * (1.f - fc);
        float w11 = fr * fc;
        float a0 = 0.f, a1 = 0.f, a2 = 0.f, a3 = 0.f;
        float a4 = 0.f, a5 = 0.f, a6 = 0.f, a7 = 0.f;
        const float* xb = x + (c8 << 3);
        #define TAP(R, C, W) \
            if ((R) < HI && (C) < WI) { \
                const float* p = xb + ((((R) << 10) + (C)) << 6); \
                float4 v0 = *(const float4*)p; \
                float4 v1 = *(const float4*)(p + 4); \
                a0 += (W) * v0.x; a1 += (W) * v0.y; a2 += (W) * v0.z; a3 += (W) * v0.w; \
                a4 += (W) * v1.x; a5 += (W) * v1.y; a6 += (W) * v1.z; a7 += (W) * v1.w; \
            }
        TAP(r0,     c0,     w00)
        TAP(r0,     c0 + 1, w01)
        TAP(r0 + 1, c0,     w10)
        TAP(r0 + 1, c0 + 1, w11)
        #undef TAP
        uint4 pk;
        pk.x = (unsigned)f2bf(a0) | ((unsigned)f2bf(a1) << 16);
        pk.y = (unsigned)f2bf(a2) | ((unsigned)f2bf(a3) << 16);
        pk.z = (unsigned)f2bf(a4) | ((unsigned)f2bf(a5) << 16);
        pk.w = (unsigned)f2bf(a6) | ((unsigned)f2bf(a7) << 16);
        *(uint4*)&xd[(((i << 9) + j) << 6) + (c8 << 3)] = pk;
    } else {
        int idx = (bid - 8192) * 256 + threadIdx.x;
        if (idx < NW) {
            int j  = idx & 7;
            int l  = (idx >> 3) & 63;
            int nf = (idx >> 9) & 7;
            int h  = (idx >> 12) & 1;
            int t  = idx >> 13;
            int cin  = (h << 5) + ((l >> 4) << 3) + j;
            int cout = (nf << 4) + (l & 15);
            float v = W1[(t * 64 + cin) * 128 + cout];
            if (t == 4) v += W2[cin * 128 + cout];   // center tap gets the 1x1 conv
            Bpk[idx] = f2bf(v);
        } else if (idx < NW + COUT) {
            int c = idx - NW;
            bf[c] = b1[c] + b2[c];
        } else if (idx < NW + COUT + 64) {
            zeroz[idx - NW - COUT] = 0;
        }
    }
}

// K2: persistent double-buffered MFMA conv (R9-proven). 256 blocks (1/CU) x 512
// threads (8 waves). Each block: 4 consecutive tiles in a row; stage tile t+1 via
// global_load_lds DMA into buf[(t+1)&1] while computing tile t from buf[t&1].
__global__ __launch_bounds__(512, 2) void k_conv(
        const unsigned short* __restrict__ xd,
        const unsigned short* __restrict__ Bpk,
        const float* __restrict__ bf,
        const unsigned short* __restrict__ zeroz,
        unsigned short* __restrict__ yb, float* __restrict__ part) {
    __shared__ short lxs[2][324 * 64];     // 2 x 18x18 halo tile x 64cin bf16 (82944 B)
    __shared__ float sred[8][32];

    const int tid = threadIdx.x;
    const int l   = tid & 63;
    const int w   = tid >> 6;
    const int trow = blockIdx.x >> 3;      // 32 tile-rows
    const int tcq  = blockIdx.x & 7;       // 8 column-quads
    const int gr0  = trow << 4;
    const int gc0b = (tcq << 2) << 4;      // first tile's gc0

    const int wq  = w & 3;                 // px quadrant
    const int wh  = w >> 2;                // cout half
    const int qg  = l >> 4;
    const int p15 = l & 15;
    const int wr0 = (wq >> 1) << 3;
    const int wc0 = (wq & 1) << 3;
    const int colbase = wc0 + (l & 7);
    int rowbase[4];
    #pragma unroll
    for (int mf = 0; mf < 4; ++mf)
        rowbase[mf] = (wr0 + 2 * mf + (p15 >> 3)) * 18 + colbase;

    const bf16x8* Bbase = (const bf16x8*)Bpk;
    // tap-0 B fragments: loaded once, resident across all 4 tiles
    bf16x8 b0[4];
    #pragma unroll
    for (int nf = 0; nf < 4; ++nf)
        b0[nf] = Bbase[(((wh << 2) + nf) << 6) + l];
    f32x4 bias4 = *(const f32x4*)&bf[(wh << 6) + (qg << 2)];

    auto STAGE = [&](int bufi, int gc0t) {
        #pragma unroll
        for (int k = 0; k < 6; ++k) {
            int idx = tid + (k << 9);
            if (idx < 324 * 8) {
                int pos = idx >> 3, c = idx & 7;
                int row = (pos * 57) >> 10;            // pos/18 for pos<324
                int col = pos - row * 18;
                int gr = gr0 + row - 1, gc = gc0t + col - 1;
                bool inpx = (gr >= 0) && (gr < HO) && (gc >= 0) && (gc < WO);
                const unsigned short* src = inpx
                    ? xd + (((gr << 9) + gc) << 6) + ((c ^ (col & 7)) << 3)
                    : zeroz;
                GLDS(src, (char*)lxs[bufi] + (((w << 6) + (k << 9)) << 4));
            }
        }
    };

    float s[4], s2[4];
    #pragma unroll
    for (int nf = 0; nf < 4; ++nf) { s[nf] = 0.f; s2[nf] = 0.f; }

    STAGE(0, gc0b);
    __syncthreads();   // prologue: tile 0 ready

    #pragma unroll 1
    for (int t = 0; t < 4; ++t) {
        if (t < 3) STAGE((t + 1) & 1, gc0b + ((t + 1) << 4));   // issue next tile's DMA

        const char* lx = (const char*)lxs[t & 1];
        const int gc0 = gc0b + (t << 4);

        f32x4 acc[4][4];
        #pragma unroll
        for (int nf = 0; nf < 4; ++nf) {
            #pragma unroll
            for (int mf = 0; mf < 4; ++mf)
                acc[mf][nf] = bias4;
        }

        bf16x8 bcur[4];
        #pragma unroll
        for (int nf = 0; nf < 4; ++nf) bcur[nf] = b0[nf];

        #pragma unroll 1
        for (int th = 0; th < 18; ++th) {
            const int thn = (th < 17) ? th + 1 : 0;
            bf16x8 bnxt[4];
            {
                const bf16x8* Bth = Bbase + (thn << 9);
                #pragma unroll
                for (int nf = 0; nf < 4; ++nf)
                    bnxt[nf] = Bth[(((wh << 2) + nf) << 6) + l];
            }
            const int tt = th >> 1;
            const int h  = th & 1;
            const int dy = (tt * 11) >> 5;   // tt/3
            const int dx = tt - dy * 3;
            const int chunkx = ((h << 2) + qg) ^ ((colbase + dx) & 7);
            bf16x8 a[4];
            #pragma unroll
            for (int mf = 0; mf < 4; ++mf)
                a[mf] = *(const bf16x8*)(lx +
                         (rowbase[mf] + dy * 18 + dx) * 128 + (chunkx << 4));
            #pragma unroll
            for (int mf = 0; mf < 4; ++mf) {
                #pragma unroll
                for (int nf = 0; nf < 4; ++nf)
                    acc[mf][nf] = __builtin_amdgcn_mfma_f32_16x16x32_bf16(
                        bcur[nf], a[mf], acc[mf][nf], 0, 0, 0);   // D^T: rows=cout, cols=px
            }
            #pragma unroll
            for (int nf = 0; nf < 4; ++nf)
                bcur[nf] = bnxt[nf];
        }

        // epilogue: lane holds couts {wh*64 + nf*16 + qg*4 .. +3} at pixel p(p15) per mf
        #pragma unroll
        for (int mf = 0; mf < 4; ++mf) {
            int gr = gr0 + wr0 + (mf << 1) + (p15 >> 3);
            int gc = gc0 + wc0 + (p15 & 7);
            unsigned short* op = yb + (((gr << 9) + gc) << 7) + (wh << 6) + (qg << 2);
            #pragma unroll
            for (int nf = 0; nf < 4; ++nf) {
                f32x4 v = acc[mf][nf];
                ushort4 o;
                o.x = f2bf(v[0]); o.y = f2bf(v[1]); o.z = f2bf(v[2]); o.w = f2bf(v[3]);
                *(ushort4*)(op + (nf << 4)) = o;
                s[nf]  += v[0] + v[1] + v[2] + v[3];
                s2[nf] += v[0] * v[0] + v[1] * v[1] + v[2] * v[2] + v[3] * v[3];
            }
        }

        __syncthreads();   // drains next tile's DMA + releases buf[t&1]
    }

    // block-level GN partials (once, after all 4 tiles)
    #pragma unroll
    for (int nf = 0; nf < 4; ++nf) {
        s[nf]  += __shfl_xor(s[nf], 1);  s[nf]  += __shfl_xor(s[nf], 2);
        s[nf]  += __shfl_xor(s[nf], 4);  s[nf]  += __shfl_xor(s[nf], 8);
        s2[nf] += __shfl_xor(s2[nf], 1); s2[nf] += __shfl_xor(s2[nf], 2);
        s2[nf] += __shfl_xor(s2[nf], 4); s2[nf] += __shfl_xor(s2[nf], 8);
    }
    if (p15 == 0) {
        #pragma unroll
        for (int nf = 0; nf < 4; ++nf) {
            sred[w][(nf << 2) + qg]      = s[nf];
            sred[w][16 + (nf << 2) + qg] = s2[nf];
        }
    }
    __syncthreads();
    if (tid < 64) {
        int isS2 = tid >> 5;         // 0: sums, 1: sumsqs
        int g    = tid & 31;         // global group
        int gh   = g >> 4;           // which cout half
        int g16  = (g & 15) + (isS2 << 4);
        float v = sred[(gh << 2) + 0][g16] + sred[(gh << 2) + 1][g16]
                + sred[(gh << 2) + 2][g16] + sred[(gh << 2) + 3][g16];
        part[(blockIdx.x << 6) + (isS2 << 5) + g] = v;
    }
}

// K3: reduce 256 block partials -> mu[g], inv_std[g]
__global__ void k_final(const float* __restrict__ part, float* __restrict__ params) {
    __shared__ float sh[256];
    int t = threadIdx.x;
    int col = t & 63, q = t >> 6;
    float s = 0.f;
    for (int r = q; r < 256; r += 4) s += part[r * 64 + col];
    sh[t] = s;
    __syncthreads();
    if (t < 64) sh[t] = sh[t] + sh[64 + t] + sh[128 + t] + sh[192 + t];
    __syncthreads();
    if (t < 32) {
        const float invN = 1.0f / (512.0f * 512.0f * 4.0f);
        float mu  = sh[t] * invN;
        float var = sh[32 + t] * invN - mu * mu;
        params[t]      = mu;
        params[32 + t] = rsqrtf(var + 1e-5f);
    }
}

// K4: normalize + scale/bias + tanh-GELU; read bf16 y from ws, write f32 to d_out.
__global__ void k_gelu(const unsigned short* __restrict__ yb, float* __restrict__ out,
                       const float* __restrict__ params, const float* __restrict__ scale,
                       const float* __restrict__ bias) {
    int t = blockIdx.x * 256 + threadIdx.x;   // 4,194,304 threads, 8 channels each
    int c0 = (t & 15) << 3;
    uint4 raw = ((const uint4*)yb)[t];
    unsigned us[8];
    us[0] = raw.x & 0xffffu; us[1] = raw.x >> 16;
    us[2] = raw.y & 0xffffu; us[3] = raw.y >> 16;
    us[4] = raw.z & 0xffffu; us[5] = raw.z >> 16;
    us[6] = raw.w & 0xffffu; us[7] = raw.w >> 16;
    int g0 = c0 >> 2;
    float mu0 = params[g0],     iv0 = params[32 + g0];
    float mu1 = params[g0 + 1], iv1 = params[33 + g0];
    float scb[8], bib[8];
    *(float4*)&scb[0] = *(const float4*)&scale[c0];
    *(float4*)&scb[4] = *(const float4*)&scale[c0 + 4];
    *(float4*)&bib[0] = *(const float4*)&bias[c0];
    *(float4*)&bib[4] = *(const float4*)&bias[c0 + 4];
    float o[8];
    #pragma unroll
    for (int k = 0; k < 8; ++k) {
        float xf = __uint_as_float(us[k] << 16);
        float mu = (k < 4) ? mu0 : mu1;
        float iv = (k < 4) ? iv0 : iv1;
        float z  = (xf - mu) * iv * scb[k] + bib[k];
        float a  = 0.7978845608028654f * (z + 0.044715f * z * z * z);
        o[k] = z / (1.0f + __expf(-2.0f * a));
    }
    float4* op = (float4*)(out + ((size_t)t << 3));
    op[0] = make_float4(o[0], o[1], o[2], o[3]);
    op[1] = make_float4(o[4], o[5], o[6], o[7]);
}

extern "C" void kernel_launch(void* const* d_in, const int* in_sizes, int n_in,
                              void* d_out, int out_size, void* d_ws, size_t ws_size,
                              hipStream_t stream) {
    const float* x  = (const float*)d_in[0];
    const float* W1 = (const float*)d_in[1];
    const float* b1 = (const float*)d_in[2];
    const float* W2 = (const float*)d_in[3];
    const float* b2 = (const float*)d_in[4];
    const float* gs = (const float*)d_in[5];
    const float* gb = (const float*)d_in[6];
    float* out = (float*)d_out;

    char* ws = (char*)d_ws;
    unsigned short* xd    = (unsigned short*)d_out;   // xd lives in d_out, dead before k_gelu
    unsigned short* yb    = (unsigned short*)(ws);
    unsigned short* Bpk   = (unsigned short*)(ws + 67108864);
    float* bf             = (float*)(ws + 67256320);
    float* part           = (float*)(ws + 67256832);
    float* params         = (float*)(ws + 67322368);
    unsigned short* zeroz = (unsigned short*)(ws + 67519232);

    k_prep<<<8192 + 289, 256, 0, stream>>>(x, W1, b1, W2, b2, xd, Bpk, bf, zeroz);
    k_conv<<<256, 512, 0, stream>>>(xd, Bpk, bf, zeroz, yb, part);
    k_final<<<1, 256, 0, stream>>>(part, params);
    k_gelu<<<(HO * WO * COUT / 8) / 256, 256, 0, stream>>>(yb, out, params, gs, gb);
}